// Round 1
// baseline (124.522 us; speedup 1.0000x reference)
//
#include <hip/hip_runtime.h>

// Spread: out[b,m] = sum_{j=0..2} x[b,m-j] * W[m,m-j] * (1+bias[m])^p(j,m)
// where p = j+1 - max(0, m-(N_IN-1)), terms dropped when m-j outside [0,N_IN).
// Derivation: the reference scan touches column m at steps n=m-2,m-1,m (valid
// subset, increasing n); each touch is o=(o + x*W)*s, so earlier contributions
// get multiplied by s once per remaining touch.

constexpr int N_IN  = 4096;
constexpr int N_OUT = 4098;   // N_IN + 2
constexpr int BATCH = 2048;
constexpr int ROWS  = 4;      // batch rows per thread (amortize coeff loads)

// Kernel 1: c[j][m] = valid ? W[m, m-j] * s^p : 0   (3 * N_OUT floats in ws)
__global__ __launch_bounds__(256) void coeff_kernel(
    const float* __restrict__ weight, const float* __restrict__ bias,
    float* __restrict__ c) {
  int m = blockIdx.x * blockDim.x + threadIdx.x;
  if (m >= N_OUT) return;
  float s  = 1.0f + bias[m];
  float s2 = s * s;
  float s3 = s2 * s;
  int red = (m > N_IN - 1) ? (m - (N_IN - 1)) : 0;  // 0,1,2 at the tail
#pragma unroll
  for (int j = 0; j < 3; ++j) {
    int n = m - j;
    float cj = 0.0f;
    if (n >= 0 && n < N_IN) {
      int pw = j + 1 - red;                    // in {1,2,3} for valid terms
      float sp = (pw == 1) ? s : ((pw == 2) ? s2 : s3);
      cj = weight[(size_t)m * N_IN + n] * sp;
    }
    c[j * N_OUT + m] = cj;
  }
}

// Kernel 2: banded matvec. Each thread computes a float2 (columns m0, m0+1)
// for ROWS consecutive batch rows. All clamped x loads are multiplied by a
// coefficient that is exactly 0 whenever the clamp engaged.
__global__ __launch_bounds__(256) void spread_kernel(
    const float* __restrict__ x, const float* __restrict__ c,
    float* __restrict__ out) {
  int pair = blockIdx.x * blockDim.x + threadIdx.x;
  if (pair >= N_OUT / 2) return;               // 2049 pairs per row
  int m0 = pair * 2;

  float c00 = c[m0],             c01 = c[m0 + 1];
  float c10 = c[N_OUT + m0],     c11 = c[N_OUT + m0 + 1];
  float c20 = c[2 * N_OUT + m0], c21 = c[2 * N_OUT + m0 + 1];

  // x window needed: x[m0-2], x[m0-1], x[m0], x[m0+1]  (clamped, even bases)
  int lo_i = (m0 >= 2) ? (m0 - 2) : 0;
  int hi_i = (m0 <= N_IN - 2) ? m0 : (N_IN - 2);

  int b0 = blockIdx.y * ROWS;
#pragma unroll
  for (int r = 0; r < ROWS; ++r) {
    int b = b0 + r;
    const float* xrow = x + (size_t)b * N_IN;
    float2 lo = *(const float2*)(xrow + lo_i);   // {x[m0-2], x[m0-1]}
    float2 hi = *(const float2*)(xrow + hi_i);   // {x[m0],   x[m0+1]}
    float o0 = c00 * hi.x + c10 * lo.y + c20 * lo.x;
    float o1 = c01 * hi.y + c11 * hi.x + c21 * lo.y;
    *(float2*)(out + (size_t)b * N_OUT + m0) = make_float2(o0, o1);
  }
}

extern "C" void kernel_launch(void* const* d_in, const int* in_sizes, int n_in,
                              void* d_out, int out_size, void* d_ws, size_t ws_size,
                              hipStream_t stream) {
  const float* x    = (const float*)d_in[0];
  const float* w    = (const float*)d_in[1];
  const float* bias = (const float*)d_in[2];
  float* out = (float*)d_out;
  float* c   = (float*)d_ws;   // 3 * N_OUT * 4 B = 49,176 B

  coeff_kernel<<<dim3((N_OUT + 255) / 256), dim3(256), 0, stream>>>(w, bias, c);

  dim3 grid((N_OUT / 2 + 255) / 256, BATCH / ROWS);  // (9, 512)
  spread_kernel<<<grid, dim3(256), 0, stream>>>(x, c, out);
}